// Round 2
// baseline (537.309 us; speedup 1.0000x reference)
//
#include <hip/hip_runtime.h>
#include <hip/hip_bf16.h>

#define C_EMB 384
#define T_SEQ 256
#define B_BATCH 128
#define M_ROWS (B_BATCH * T_SEQ)   // 32768
#define QKV_LD 1152                // row stride of qkv buffer (bf16)
#define BK 64                      // K-tile = two 32-elem panels (each 64-B rows, m97 layout)

typedef __bf16 bf16_8 __attribute__((ext_vector_type(8)));
typedef float f32x4 __attribute__((ext_vector_type(4)));

// Async global->LDS 16-B copy. Dest is wave-uniform base + lane*16 (m104/m108).
__device__ __forceinline__ void load16_lds(const __bf16* g, __bf16* l) {
    __builtin_amdgcn_global_load_lds(
        (const __attribute__((address_space(1))) unsigned int*)g,
        (__attribute__((address_space(3))) unsigned int*)l, 16, 0, 0);
}

// ---------------- All-weights cast + transpose (single dispatch) ----------------------
// Wt[n][k] = bf16(W[k][n]) for the 4 weight matrices; block ranges select the matrix.
__global__ __launch_bounds__(256) void cast_all_kernel(const float* __restrict__ Wa,
                                                       const float* __restrict__ Wp,
                                                       const float* __restrict__ W1,
                                                       const float* __restrict__ W2,
                                                       __bf16* __restrict__ Wa_t,
                                                       __bf16* __restrict__ Wp_t,
                                                       __bf16* __restrict__ W1_t,
                                                       __bf16* __restrict__ W2_t) {
    int bid = blockIdx.x;
    const float* W; __bf16* Wt; int K, N, tx_n;
    // tile counts: Wa 36x12=432, Wp 12x12=144, W1 48x12=576, W2 12x48=576
    if (bid < 432)      { W = Wa; Wt = Wa_t; K = 384;  N = 1152; tx_n = 36; }
    else if (bid < 576) { bid -= 432; W = Wp; Wt = Wp_t; K = 384;  N = 384;  tx_n = 12; }
    else if (bid < 1152){ bid -= 576; W = W1; Wt = W1_t; K = 384;  N = 1536; tx_n = 48; }
    else                { bid -= 1152; W = W2; Wt = W2_t; K = 1536; N = 384;  tx_n = 12; }
    int n0 = (bid % tx_n) * 32, k0 = (bid / tx_n) * 32;

    __shared__ float t[32][33];
    int tx = threadIdx.x & 31, ty = threadIdx.x >> 5;
#pragma unroll
    for (int i = 0; i < 4; ++i)
        t[ty + i * 8][tx] = W[(size_t)(k0 + ty + i * 8) * N + n0 + tx];
    __syncthreads();
#pragma unroll
    for (int i = 0; i < 4; ++i) {
        int n = ty + i * 8;
        Wt[(size_t)(n0 + n) * K + k0 + tx] = (__bf16)t[tx][n];
    }
}

// ---------------- LayerNorm: one block (384 threads) per row, bf16 out ----------------
__global__ __launch_bounds__(384) void ln_kernel(const float* __restrict__ x,
                                                 const float* __restrict__ g,
                                                 const float* __restrict__ bta,
                                                 __bf16* __restrict__ out) {
    int row = blockIdx.x;
    int c = threadIdx.x;
    float v = x[(size_t)row * C_EMB + c];

    __shared__ float red[6];
    float s = v;
#pragma unroll
    for (int o = 32; o; o >>= 1) s += __shfl_down(s, o);
    if ((c & 63) == 0) red[c >> 6] = s;
    __syncthreads();
    float mu = (red[0] + red[1] + red[2] + red[3] + red[4] + red[5]) * (1.0f / C_EMB);

    float d = v - mu;
    float s2 = d * d;
#pragma unroll
    for (int o = 32; o; o >>= 1) s2 += __shfl_down(s2, o);
    __syncthreads();
    if ((c & 63) == 0) red[c >> 6] = s2;
    __syncthreads();
    float var = (red[0] + red[1] + red[2] + red[3] + red[4] + red[5]) * (1.0f / C_EMB);

    out[(size_t)row * C_EMB + c] = (__bf16)(d * rsqrtf(var + 1e-5f) * g[c] + bta[c]);
}

// ---------------- bf16 MFMA GEMM: out = A[M,K](lda) @ Bt[N,K](ldb)^T + bias ----------
// TM x 128 tile, 256 thr = 2x2 waves. BK=64 as two 32-elem panels; each panel is the
// m97-verified unpadded 64-B-row LDS layout (bank geometry preserved), one barrier
// pair per 64 K.
template <int TM, bool RELU, bool RESID, bool OUT_BF16>
__global__ __launch_bounds__(256) void mfma_gemm(const __bf16* __restrict__ A, int lda,
                                                 const __bf16* __restrict__ Bt, int ldb,
                                                 const float* __restrict__ bias,
                                                 const float* __restrict__ resid,
                                                 void* __restrict__ out_,
                                                 int N, int K) {
    constexpr int MI = TM / 32;      // acc m-tiles per wave
    constexpr int WROWS = TM / 2;    // wave quadrant rows
    __shared__ __align__(16) __bf16 As[2 * TM * 32];
    __shared__ __align__(16) __bf16 Bs[2 * 128 * 32];

    int tid = threadIdx.x;
    int wave = tid >> 6, lane = tid & 63;
    int wr = wave >> 1, wc = wave & 1;
    int quad = lane >> 4, l16 = lane & 15;
    int bm = blockIdx.y * TM, bn = blockIdx.x * 128;
    int lrow = lane >> 2, lcol = (lane & 3) * 8;   // 16 rows x 4 chunks per wave-issue

    f32x4 acc[MI][4] = {};

    for (int k0 = 0; k0 < K; k0 += BK) {
        const __bf16* Ab = A + (size_t)bm * lda + k0;
        const __bf16* Bb = Bt + (size_t)bn * ldb + k0;
#pragma unroll
        for (int p = 0; p < 2; ++p) {
#pragma unroll
            for (int i = 0; i < TM / 64; ++i) {
                int r0 = (i * 4 + wave) * 16;
                load16_lds(Ab + (size_t)(r0 + lrow) * lda + p * 32 + lcol,
                           &As[p * TM * 32 + r0 * 32]);
            }
#pragma unroll
            for (int i = 0; i < 2; ++i) {
                int r0 = (i * 4 + wave) * 16;
                load16_lds(Bb + (size_t)(r0 + lrow) * ldb + p * 32 + lcol,
                           &Bs[p * 128 * 32 + r0 * 32]);
            }
        }
        __syncthreads();

        bf16_8 af[MI][2], bf[4][2];
#pragma unroll
        for (int p = 0; p < 2; ++p) {
#pragma unroll
            for (int i = 0; i < MI; ++i)
                af[i][p] = *reinterpret_cast<const bf16_8*>(
                    &As[p * TM * 32 + (wr * WROWS + i * 16 + l16) * 32 + quad * 8]);
#pragma unroll
            for (int j = 0; j < 4; ++j)
                bf[j][p] = *reinterpret_cast<const bf16_8*>(
                    &Bs[p * 128 * 32 + (wc * 64 + j * 16 + l16) * 32 + quad * 8]);
        }
#pragma unroll
        for (int i = 0; i < MI; ++i)
#pragma unroll
            for (int j = 0; j < 4; ++j) {
                acc[i][j] = __builtin_amdgcn_mfma_f32_16x16x32_bf16(af[i][0], bf[j][0], acc[i][j], 0, 0, 0);
                acc[i][j] = __builtin_amdgcn_mfma_f32_16x16x32_bf16(af[i][1], bf[j][1], acc[i][j], 0, 0, 0);
            }
        __syncthreads();
    }

    // C/D layout: col = lane&15, row = quad*4 + r  [m89-verified]
#pragma unroll
    for (int i = 0; i < MI; ++i) {
#pragma unroll
        for (int r = 0; r < 4; ++r) {
            int m = bm + wr * WROWS + i * 16 + quad * 4 + r;
#pragma unroll
            for (int j = 0; j < 4; ++j) {
                int n = bn + wc * 64 + j * 16 + l16;
                float v = acc[i][j][r] + bias[n];
                if (RELU) v = fmaxf(v, 0.0f);
                if (RESID) v += resid[(size_t)m * N + n];
                if (OUT_BF16)
                    ((__bf16*)out_)[(size_t)m * N + n] = (__bf16)v;
                else
                    ((float*)out_)[(size_t)m * N + n] = v;
            }
        }
    }
}

// ---------------- Fused MLP: out += relu(h2 @ W1 + b1) @ W2 + b2 ----------------------
// One block = 64 rows, 256 thr (2x2 waves). Hidden dim (1536) looped in 24 chunks of 64:
//   stage1: P[64,64] = relu(h2_tile @ W1[c*64:+64, :]^T + b1)   (h2 frags in REGISTERS)
//   stage2: acc2[64,384] += P @ W2[:, c*64:+64]^T
// W-chunk tiles (48 KB) share one LDS buffer, staged by global_load_lds with a
// pre-swizzled global source (m173): 128-B LDS rows, 16-B unit ^= (row&7) -> the 8-way
// ds_read_b128 bank conflict of the linear layout becomes 2-way (free, m136).
// P round-trips through an 8 KB LDS panel with the same swizzle.
__global__ __launch_bounds__(256, 2) void mlp_fused(const __bf16* __restrict__ h2,
                                                    const __bf16* __restrict__ W1t,   // [1536,384]
                                                    const __bf16* __restrict__ W2t,   // [384,1536]
                                                    const float* __restrict__ b1,
                                                    const float* __restrict__ b2,
                                                    float* __restrict__ out) {        // [M,384] in-place +=
    __shared__ __align__(16) __bf16 Bs[24576];  // 48KB: W1-tile [6][64][64]  OR  W2-tile [384][64]
    __shared__ __align__(16) __bf16 Ps[4096];   // 8KB: P [64][64], swizzled

    int tid = threadIdx.x;
    int wave = tid >> 6, lane = tid & 63;
    int wr = wave >> 1, wc = wave & 1;
    int quad = lane >> 4, l16 = lane & 15;
    int bm = blockIdx.x * 64;

    // staging source swizzle: lane covers (row = base + lane>>3, 16B-unit = lane&7);
    // source unit pre-XORed so LDS stays linear (load16_lds requirement, m104/m173)
    int srow = lane >> 3;              // row within 8-row group == row&7 (bases are x8)
    int sunit = (lane & 7) ^ srow;     // swizzled source 16-B unit

    // h2 A-fragments in registers: af1[i][p] row = bm+wr*32+i*16+l16, k = p*32+quad*8
    bf16_8 af1[2][12];
    {
        const __bf16* h0 = h2 + (size_t)(bm + wr * 32 + l16) * C_EMB + quad * 8;
#pragma unroll
        for (int i = 0; i < 2; ++i)
#pragma unroll
            for (int p = 0; p < 12; ++p)
                af1[i][p] = *reinterpret_cast<const bf16_8*>(h0 + i * 16 * C_EMB + p * 32);
    }

    f32x4 acc2[2][12] = {};

    for (int c = 0; c < 24; ++c) {
        // ---- phase 1: stage W1-tile rows [c*64, c*64+64), all 384 k (6 panels) ----
        __syncthreads();
        {
            const __bf16* src = W1t + (size_t)(c * 64 + srow) * C_EMB + sunit * 8;
#pragma unroll
            for (int t = 0; t < 12; ++t) {
                int g = t * 4 + wave;          // 0..47
                int kp = g >> 3, rg = g & 7;   // panel, 8-row group
                load16_lds(src + (size_t)(rg * 8) * C_EMB + kp * 64,
                           &Bs[kp * 4096 + rg * 8 * 64]);
            }
        }
        __syncthreads();

        // ---- stage-1 MFMA: pacc = h2 @ W1-tile^T ----
        f32x4 pacc[2][2] = {};
#pragma unroll
        for (int p = 0; p < 12; ++p) {
            int kp = p >> 1;
            bf16_8 bf[2];
#pragma unroll
            for (int j = 0; j < 2; ++j) {
                int row = wc * 32 + j * 16 + l16;
                int unit = (((p & 1) * 4 + quad) ^ (row & 7));
                bf[j] = *reinterpret_cast<const bf16_8*>(&Bs[kp * 4096 + row * 64 + unit * 8]);
            }
#pragma unroll
            for (int i = 0; i < 2; ++i)
#pragma unroll
                for (int j = 0; j < 2; ++j)
                    pacc[i][j] = __builtin_amdgcn_mfma_f32_16x16x32_bf16(af1[i][p], bf[j], pacc[i][j], 0, 0, 0);
        }

        // ---- phase 2: stage W2-tile (cols c*64..+63, all 384 n) + write P to LDS ----
        __syncthreads();
        {
            const __bf16* src = W2t + (size_t)srow * 1536 + c * 64 + sunit * 8;
#pragma unroll
            for (int t = 0; t < 12; ++t) {
                int g = t * 4 + wave;          // rows g*8 .. g*8+7
                load16_lds(src + (size_t)(g * 8) * 1536, &Bs[g * 8 * 64]);
            }
        }
        // P = relu(pacc + b1), bf16, swizzled store (C/D layout: col=l16, row=quad*4+r)
#pragma unroll
        for (int i = 0; i < 2; ++i)
#pragma unroll
            for (int j = 0; j < 2; ++j) {
                int col = wc * 32 + j * 16 + l16;
                float bb = b1[c * 64 + col];
                int unit0 = col >> 3, cw = col & 7;
#pragma unroll
                for (int r = 0; r < 4; ++r) {
                    int row = wr * 32 + i * 16 + quad * 4 + r;
                    float v = fmaxf(pacc[i][j][r] + bb, 0.0f);
                    Ps[row * 64 + ((unit0 ^ (row & 7)) << 3) + cw] = (__bf16)v;
                }
            }
        __syncthreads();

        // ---- stage-2 MFMA: acc2 += P @ W2-tile^T ----
#pragma unroll
        for (int p = 0; p < 2; ++p) {
            bf16_8 pf[2];
#pragma unroll
            for (int i = 0; i < 2; ++i) {
                int row = wr * 32 + i * 16 + l16;
                int unit = ((p * 4 + quad) ^ (row & 7));
                pf[i] = *reinterpret_cast<const bf16_8*>(&Ps[row * 64 + unit * 8]);
            }
#pragma unroll
            for (int j = 0; j < 12; ++j) {
                int row = wc * 192 + j * 16 + l16;
                int unit = ((p * 4 + quad) ^ (row & 7));
                bf16_8 bf = *reinterpret_cast<const bf16_8*>(&Bs[row * 64 + unit * 8]);
#pragma unroll
                for (int i = 0; i < 2; ++i)
                    acc2[i][j] = __builtin_amdgcn_mfma_f32_16x16x32_bf16(pf[i], bf, acc2[i][j], 0, 0, 0);
            }
        }
    }

    // ---- epilogue: out += acc2 + b2 (fp32 read-modify-write, one writer/element) ----
#pragma unroll
    for (int i = 0; i < 2; ++i)
#pragma unroll
        for (int r = 0; r < 4; ++r) {
            int m = bm + wr * 32 + i * 16 + quad * 4 + r;
#pragma unroll
            for (int j = 0; j < 12; ++j) {
                int n = wc * 192 + j * 16 + l16;
                float* o = &out[(size_t)m * C_EMB + n];
                *o = *o + acc2[i][j][r] + b2[n];
            }
        }
}

// ---------------- V transpose: Vt[b][c][s] = qkv[b][s][768+c] -------------------------
__global__ __launch_bounds__(256) void vt_kernel(const __bf16* __restrict__ qkv,
                                                 __bf16* __restrict__ Vt) {
    __shared__ __align__(16) __bf16 t[32][72];
    int b = blockIdx.z, c0 = blockIdx.x * 64, s0 = blockIdx.y * 32;
    int tid = threadIdx.x;

    int tx = tid & 7, ty = tid >> 3;
    const __bf16* src = qkv + ((size_t)b * T_SEQ + s0 + ty) * QKV_LD + 768 + c0 + tx * 8;
    *reinterpret_cast<float4*>(&t[ty][tx * 8]) = *reinterpret_cast<const float4*>(src);
    __syncthreads();

    int sx = tid & 3, cy = tid >> 2;
    __align__(16) __bf16 tmp[8];
#pragma unroll
    for (int j = 0; j < 8; ++j) tmp[j] = t[sx * 8 + j][cy];
    *reinterpret_cast<float4*>(&Vt[((size_t)b * C_EMB + c0 + cy) * T_SEQ + s0 + sx * 8]) =
        *reinterpret_cast<float4*>(tmp);
}

// ---------------- Attention pass 1: S = scale * Q @ K^T (MFMA, tri-tiles) -------------
__global__ __launch_bounds__(256) void qk_mfma(const __bf16* __restrict__ qkv,
                                               float* __restrict__ S) {
    static const int TMt[3] = {0, 1, 1};
    static const int TNt[3] = {0, 0, 1};
    int b = blockIdx.y;
    int bm = TMt[blockIdx.x] * 128, bn = TNt[blockIdx.x] * 128;
    const __bf16* Ab0 = qkv + (size_t)b * T_SEQ * QKV_LD;
    const __bf16* Bb0 = Ab0 + 384;

    __shared__ __align__(16) __bf16 As[2 * 128 * 32];
    __shared__ __align__(16) __bf16 Bs[2 * 128 * 32];

    int tid = threadIdx.x;
    int wave = tid >> 6, lane = tid & 63;
    int wr = wave >> 1, wc = wave & 1;
    int quad = lane >> 4, l16 = lane & 15;
    int lrow = lane >> 2, lcol = (lane & 3) * 8;

    f32x4 acc[4][4] = {};

    for (int k0 = 0; k0 < C_EMB; k0 += BK) {
        const __bf16* Ab = Ab0 + (size_t)bm * QKV_LD + k0;
        const __bf16* Bb = Bb0 + (size_t)bn * QKV_LD + k0;
#pragma unroll
        for (int p = 0; p < 2; ++p)
#pragma unroll
            for (int i = 0; i < 2; ++i) {
                int r0 = (i * 4 + wave) * 16;
                load16_lds(Ab + (size_t)(r0 + lrow) * QKV_LD + p * 32 + lcol,
                           &As[p * 128 * 32 + r0 * 32]);
                load16_lds(Bb + (size_t)(r0 + lrow) * QKV_LD + p * 32 + lcol,
                           &Bs[p * 128 * 32 + r0 * 32]);
            }
        __syncthreads();

        bf16_8 af[4][2], bf[4][2];
#pragma unroll
        for (int p = 0; p < 2; ++p)
#pragma unroll
            for (int i = 0; i < 4; ++i) {
                af[i][p] = *reinterpret_cast<const bf16_8*>(
                    &As[p * 128 * 32 + (wr * 64 + i * 16 + l16) * 32 + quad * 8]);
                bf[i][p] = *reinterpret_cast<const bf16_8*>(
                    &Bs[p * 128 * 32 + (wc * 64 + i * 16 + l16) * 32 + quad * 8]);
            }
#pragma unroll
        for (int i = 0; i < 4; ++i)
#pragma unroll
            for (int j = 0; j < 4; ++j) {
                acc[i][j] = __builtin_amdgcn_mfma_f32_16x16x32_bf16(af[i][0], bf[j][0], acc[i][j], 0, 0, 0);
                acc[i][j] = __builtin_amdgcn_mfma_f32_16x16x32_bf16(af[i][1], bf[j][1], acc[i][j], 0, 0, 0);
            }
        __syncthreads();
    }

    float* Sb = S + (size_t)b * T_SEQ * T_SEQ;
#pragma unroll
    for (int i = 0; i < 4; ++i) {
#pragma unroll
        for (int r = 0; r < 4; ++r) {
            int m = bm + wr * 64 + i * 16 + quad * 4 + r;
#pragma unroll
            for (int j = 0; j < 4; ++j) {
                int n = bn + wc * 64 + j * 16 + l16;
                Sb[(size_t)m * T_SEQ + n] = acc[i][j][r] * 0.05103103630798288f;
            }
        }
    }
}

// ---------------- Attention pass 2: causal softmax, fp32 S → bf16 P -------------------
__global__ __launch_bounds__(256) void softmax_kernel(const float* __restrict__ S,
                                                      __bf16* __restrict__ P) {
    int row = blockIdx.x;
    int t = row & (T_SEQ - 1);
    int tid = threadIdx.x;
    const float* Sr = S + (size_t)row * T_SEQ;

    __shared__ float red[4];
    float sc = (tid <= t) ? Sr[tid] : -INFINITY;

    float mx = sc;
#pragma unroll
    for (int o = 32; o; o >>= 1) mx = fmaxf(mx, __shfl_down(mx, o));
    if ((tid & 63) == 0) red[tid >> 6] = mx;
    __syncthreads();
    mx = fmaxf(fmaxf(red[0], red[1]), fmaxf(red[2], red[3]));

    float p = (tid <= t) ? __expf(sc - mx) : 0.0f;
    float sm = p;
#pragma unroll
    for (int o = 32; o; o >>= 1) sm += __shfl_down(sm, o);
    __syncthreads();
    if ((tid & 63) == 0) red[tid >> 6] = sm;
    __syncthreads();
    sm = red[0] + red[1] + red[2] + red[3];

    P[(size_t)row * T_SEQ + tid] = (__bf16)(p / sm);
}

// ---------------- Attention pass 3: y = P @ V (MFMA, causal k-skip) -------------------
__global__ __launch_bounds__(256) void pv_mfma(const __bf16* __restrict__ P,
                                               const __bf16* __restrict__ Vt,
                                               __bf16* __restrict__ y) {
    int b = blockIdx.z;
    int bm = blockIdx.y * 128, bn = blockIdx.x * 128;
    const __bf16* Ab0 = P + (size_t)b * T_SEQ * T_SEQ;
    const __bf16* Bb0 = Vt + (size_t)b * C_EMB * T_SEQ;

    __shared__ __align__(16) __bf16 As[2 * 128 * 32];
    __shared__ __align__(16) __bf16 Bs[2 * 128 * 32];

    int tid = threadIdx.x;
    int wave = tid >> 6, lane = tid & 63;
    int wr = wave >> 1, wc = wave & 1;
    int quad = lane >> 4, l16 = lane & 15;
    int lrow = lane >> 2, lcol = (lane & 3) * 8;

    f32x4 acc[4][4] = {};

    int kmax = bm + 128;   // divisible by 64
    for (int k0 = 0; k0 < kmax; k0 += BK) {
        const __bf16* Ab = Ab0 + (size_t)bm * T_SEQ + k0;
        const __bf16* Bb = Bb0 + (size_t)bn * T_SEQ + k0;
#pragma unroll
        for (int p = 0; p < 2; ++p)
#pragma unroll
            for (int i = 0; i < 2; ++i) {
                int r0 = (i * 4 + wave) * 16;
                load16_lds(Ab + (size_t)(r0 + lrow) * T_SEQ + p * 32 + lcol,
                           &As[p * 128 * 32 + r0 * 32]);
                load16_lds(Bb + (size_t)(r0 + lrow) * T_SEQ + p * 32 + lcol,
                           &Bs[p * 128 * 32 + r0 * 32]);
            }
        __syncthreads();

        bf16_8 af[4][2], bf[4][2];
#pragma unroll
        for (int p = 0; p < 2; ++p)
#pragma unroll
            for (int i = 0; i < 4; ++i) {
                af[i][p] = *reinterpret_cast<const bf16_8*>(
                    &As[p * 128 * 32 + (wr * 64 + i * 16 + l16) * 32 + quad * 8]);
                bf[i][p] = *reinterpret_cast<const bf16_8*>(
                    &Bs[p * 128 * 32 + (wc * 64 + i * 16 + l16) * 32 + quad * 8]);
            }
#pragma unroll
        for (int i = 0; i < 4; ++i)
#pragma unroll
            for (int j = 0; j < 4; ++j) {
                acc[i][j] = __builtin_amdgcn_mfma_f32_16x16x32_bf16(af[i][0], bf[j][0], acc[i][j], 0, 0, 0);
                acc[i][j] = __builtin_amdgcn_mfma_f32_16x16x32_bf16(af[i][1], bf[j][1], acc[i][j], 0, 0, 0);
            }
        __syncthreads();
    }

#pragma unroll
    for (int i = 0; i < 4; ++i) {
#pragma unroll
        for (int r = 0; r < 4; ++r) {
            int m = bm + wr * 64 + i * 16 + quad * 4 + r;
#pragma unroll
            for (int j = 0; j < 4; ++j) {
                int n = bn + wc * 64 + j * 16 + l16;
                y[((size_t)b * T_SEQ + m) * C_EMB + n] = (__bf16)acc[i][j][r];
            }
        }
    }
}

extern "C" void kernel_launch(void* const* d_in, const int* in_sizes, int n_in,
                              void* d_out, int out_size, void* d_ws, size_t ws_size,
                              hipStream_t stream) {
    const float* x      = (const float*)d_in[0];
    const float* W_attn = (const float*)d_in[1];
    const float* b_attn = (const float*)d_in[2];
    const float* W_proj = (const float*)d_in[3];
    const float* b_proj = (const float*)d_in[4];
    const float* ln1_g  = (const float*)d_in[5];
    const float* ln1_b  = (const float*)d_in[6];
    const float* ln2_g  = (const float*)d_in[7];
    const float* ln2_b  = (const float*)d_in[8];
    const float* W1     = (const float*)d_in[9];
    const float* b1     = (const float*)d_in[10];
    const float* W2     = (const float*)d_in[11];
    const float* b2     = (const float*)d_in[12];
    float* out = (float*)d_out;

    // ---- workspace (205 MB; ws >= 251.6 MB proven) ----
    __bf16* Wattn_t = (__bf16*)d_ws;                            // [1152,384]
    __bf16* Wproj_t = Wattn_t + (size_t)1152 * 384;             // [384,384]
    __bf16* W1_t    = Wproj_t + (size_t)384 * 384;              // [1536,384]
    __bf16* W2_t    = W1_t + (size_t)1536 * 384;                // [384,1536]
    __bf16* h       = W2_t + (size_t)384 * 1536;                // [M,384] bf16
    __bf16* yb      = h + (size_t)M_ROWS * 384;                 // [M,384] bf16
    __bf16* qkv     = yb + (size_t)M_ROWS * 384;                // [M,1152] bf16
    float*  S       = (float*)(qkv + (size_t)M_ROWS * QKV_LD);  // [B,T,T] fp32
    __bf16* Pb      = (__bf16*)(S + (size_t)B_BATCH * T_SEQ * T_SEQ);  // [B,T,T] bf16
    __bf16* Vt      = Pb + (size_t)B_BATCH * T_SEQ * T_SEQ;     // [B,384,T] bf16

    // 0. weights → bf16 [N,K], one dispatch (432+144+576+576 = 1728 tiles)
    cast_all_kernel<<<1728, 256, 0, stream>>>(W_attn, W_proj, W1, W2,
                                              Wattn_t, Wproj_t, W1_t, W2_t);

    // 1. h = bf16(LN1(x))
    ln_kernel<<<M_ROWS, 384, 0, stream>>>(x, ln1_g, ln1_b, h);
    // 2. qkv = bf16(h @ W_attn + b_attn)
    mfma_gemm<128, false, false, true><<<dim3(1152 / 128, M_ROWS / 128), 256, 0, stream>>>(
        h, 384, Wattn_t, 384, b_attn, nullptr, qkv, 1152, 384);
    // 3. attention (bf16 MFMA core)
    vt_kernel<<<dim3(C_EMB / 64, T_SEQ / 32, B_BATCH), 256, 0, stream>>>(qkv, Vt);
    qk_mfma<<<dim3(3, B_BATCH), 256, 0, stream>>>(qkv, S);
    softmax_kernel<<<M_ROWS, 256, 0, stream>>>(S, Pb);
    pv_mfma<<<dim3(C_EMB / 128, T_SEQ / 128, B_BATCH), 256, 0, stream>>>(Pb, Vt, yb);
    // 4. out = x + yb @ W_proj + b_proj   (TM=64: 6 blocks/CU)
    mfma_gemm<64, false, true, false><<<dim3(384 / 128, M_ROWS / 64), 256, 0, stream>>>(
        yb, 384, Wproj_t, 384, b_proj, x, out, 384, 384);
    // 5. h2 = bf16(LN2(out))
    ln_kernel<<<M_ROWS, 384, 0, stream>>>(out, ln2_g, ln2_b, h);
    // 6+7. out += relu(h2 @ W1 + b1) @ W2 + b2   (fused MLP, no ff intermediate)
    mlp_fused<<<M_ROWS / 64, 256, 0, stream>>>(h, W1_t, W2_t, b1, b2, out);
}